// Round 2
// baseline (363.631 us; speedup 1.0000x reference)
//
#include <hip/hip_runtime.h>

// LightweightConv1d: x (T,B,C) f32, weight (H,1,K) f32 (softmax over K), bias (C) f32
// out[t,b,c] = bias[c] + sum_k softmax(w[h])[k] * x[t-P+k, b, c],  h = c / (C/H)
#define T_DIM 2048
#define B_DIM 32
#define C_DIM 512
#define H_DIM 16
#define K_DIM 31
#define P_PAD 15
#define SEG 32
#define SEGLEN (T_DIM / SEG)     // 64 time-steps per thread
#define TT 16                    // chunk of outputs per iteration
#define WIN (TT + K_DIM - 1)     // 46-element register sliding window
#define STRIDE (B_DIM * C_DIM)   // 16384 floats between consecutive t

__global__ __launch_bounds__(256, 8)
void lwconv_kernel(const float* __restrict__ x, const float* __restrict__ weight,
                   const float* __restrict__ bias, float* __restrict__ out)
{
    const int bid = blockIdx.x;
    const int c   = ((bid & 1) << 8) | threadIdx.x;   // lane -> consecutive c (coalesced)
    const int b   = (bid >> 1) & (B_DIM - 1);
    const int seg = bid >> 6;
    const int h   = c >> 5;                           // c / (C/H), R = 32

    // per-thread softmax of the 31 head weights (fp32, max-subtracted)
    float w[K_DIM];
    float m = -3.4e38f;
    #pragma unroll
    for (int k = 0; k < K_DIM; ++k) { w[k] = weight[h * K_DIM + k]; m = fmaxf(m, w[k]); }
    float s = 0.f;
    #pragma unroll
    for (int k = 0; k < K_DIM; ++k) { w[k] = __expf(w[k] - m); s += w[k]; }
    const float inv = 1.f / s;
    #pragma unroll
    for (int k = 0; k < K_DIM; ++k) w[k] *= inv;

    const float bv = bias[c];
    const float* xp = x + (size_t)b * C_DIM + c;
    float*       op = out + (size_t)b * C_DIM + c;
    const int t0 = seg * SEGLEN;

    // Preload left halo: xw[0..29] = x[t0-15 .. t0+14] (zero below t=0).
    // Upper bound never hit: t0+14 <= 1998 < 2048.
    float xw[WIN];
    #pragma unroll
    for (int i = 0; i < K_DIM - 1; ++i) {
        int t = t0 - P_PAD + i;
        xw[i] = (t >= 0) ? xp[(size_t)t * STRIDE] : 0.f;
    }

    #pragma unroll 1   // keep the chunk loop rolled: small icache footprint
    for (int chunk = 0; chunk < SEGLEN / TT; ++chunk) {
        const int tb = t0 + chunk * TT;   // outputs tb .. tb+TT-1
        // load leading edge: xw[30..45] = x[tb+15 .. tb+30] (zero past T)
        #pragma unroll
        for (int i = 0; i < TT; ++i) {
            int t = tb + P_PAD + i;
            xw[K_DIM - 1 + i] = (t < T_DIM) ? xp[(size_t)t * STRIDE] : 0.f;
        }
        // compute + store 16 outputs, all static indexing
        #pragma unroll
        for (int i = 0; i < TT; ++i) {
            float acc = bv;
            #pragma unroll
            for (int k = 0; k < K_DIM; ++k) acc = fmaf(w[k], xw[i + k], acc);
            op[(size_t)(tb + i) * STRIDE] = acc;
        }
        // shift window left by TT
        #pragma unroll
        for (int i = 0; i < K_DIM - 1; ++i) xw[i] = xw[i + TT];
    }
}

extern "C" void kernel_launch(void* const* d_in, const int* in_sizes, int n_in,
                              void* d_out, int out_size, void* d_ws, size_t ws_size,
                              hipStream_t stream) {
    const float* x      = (const float*)d_in[0];
    const float* weight = (const float*)d_in[1];
    const float* bias   = (const float*)d_in[2];
    float* out = (float*)d_out;
    dim3 grid(2 * B_DIM * SEG);   // c_hi(2) * b(32) * seg(32) = 2048 blocks
    dim3 block(256);
    lwconv_kernel<<<grid, block, 0, stream>>>(x, weight, bias, out);
}

// Round 3
// 61.281 us; speedup vs baseline: 5.9338x; 5.9338x over previous
//
#include <hip/hip_runtime.h>

// LightweightConv1d: x (T,B,C) f32, weight (H,1,K) f32 (softmax over K), bias (C) f32
// out[t,b,c] = bias[c] + sum_k softmax(w[h])[k] * x[t-P+k, b, c],  h = c / (C/H)
#define T_DIM 2048
#define B_DIM 32
#define C_DIM 512
#define H_DIM 16
#define K_DIM 31
#define P_PAD 15
#define SEG 32
#define SEGLEN (T_DIM / SEG)     // 64 time-steps per thread
#define TT 8                     // chunk of outputs per iteration
#define WIN (TT + K_DIM - 1)     // 38-element register sliding window
#define STRIDE (B_DIM * C_DIM)   // 16384 floats between consecutive t

// Wave-per-head mapping: each 64-lane wave = 32 channels of ONE head x 2 batches.
// Head index is wave-uniform -> softmaxed weights live in SGPRs (readfirstlane),
// freeing 31 VGPRs so the 38-reg sliding window fits a 64-VGPR budget (8 waves/EU).
__global__ __launch_bounds__(256, 8)
void lwconv_kernel(const float* __restrict__ x, const float* __restrict__ weight,
                   const float* __restrict__ bias, float* __restrict__ out)
{
    const int wid  = __builtin_amdgcn_readfirstlane((int)(threadIdx.x >> 6)); // wave id, scalar
    const int lane = threadIdx.x & 63;
    const int g    = blockIdx.x * 4 + wid;        // global wave id, scalar
    const int h    = g & (H_DIM - 1);             // head (uniform)
    const int bp   = (g >> 4) & 15;               // batch pair (uniform)
    const int seg  = g >> 8;                      // t-segment 0..31 (uniform)
    const int c    = (h << 5) | (lane & 31);      // 32 channels of head h
    const int b    = (bp << 1) | (lane >> 5);     // 2 batches per wave

    // per-lane softmax of the head's 31 weights (uniform inputs), then -> SGPR
    float w[K_DIM];
    float m = -3.4e38f;
    #pragma unroll
    for (int k = 0; k < K_DIM; ++k) { w[k] = weight[h * K_DIM + k]; m = fmaxf(m, w[k]); }
    float s = 0.f;
    #pragma unroll
    for (int k = 0; k < K_DIM; ++k) { w[k] = __expf(w[k] - m); s += w[k]; }
    const float inv = 1.f / s;
    unsigned int ws[K_DIM];
    #pragma unroll
    for (int k = 0; k < K_DIM; ++k)
        ws[k] = __builtin_amdgcn_readfirstlane(__float_as_uint(w[k] * inv));

    const float bv = bias[c];
    const float* xp = x + (size_t)b * C_DIM + c;
    float*       op = out + (size_t)b * C_DIM + c;
    const int t0 = seg * SEGLEN;

    // Preload left halo: xw[0..29] = x[t0-15 .. t0+14] (zero below t=0).
    // Upper bound never hit: t0+14 <= 1998 < 2048.
    float xw[WIN];
    #pragma unroll
    for (int i = 0; i < K_DIM - 1; ++i) {
        int t = t0 - P_PAD + i;
        xw[i] = (t >= 0) ? xp[(size_t)t * STRIDE] : 0.f;
    }

    #pragma unroll 1   // keep chunk loop rolled: small icache, bounded live range
    for (int chunk = 0; chunk < SEGLEN / TT; ++chunk) {
        const int tb = t0 + chunk * TT;   // outputs tb .. tb+TT-1
        // load leading edge: xw[30..37] = x[tb+15 .. tb+22] (zero past T)
        #pragma unroll
        for (int i = 0; i < TT; ++i) {
            int t = tb + P_PAD + i;
            xw[K_DIM - 1 + i] = (t < T_DIM) ? xp[(size_t)t * STRIDE] : 0.f;
        }
        // compute + store TT outputs, all static indexing, weights from SGPR
        #pragma unroll
        for (int i = 0; i < TT; ++i) {
            float acc = bv;
            #pragma unroll
            for (int k = 0; k < K_DIM; ++k)
                acc = fmaf(__uint_as_float(ws[k]), xw[i + k], acc);
            op[(size_t)(tb + i) * STRIDE] = acc;
        }
        // shift window left by TT
        #pragma unroll
        for (int i = 0; i < WIN - TT; ++i) xw[i] = xw[i + TT];
    }
}

extern "C" void kernel_launch(void* const* d_in, const int* in_sizes, int n_in,
                              void* d_out, int out_size, void* d_ws, size_t ws_size,
                              hipStream_t stream) {
    const float* x      = (const float*)d_in[0];
    const float* weight = (const float*)d_in[1];
    const float* bias   = (const float*)d_in[2];
    float* out = (float*)d_out;
    // waves = H(16) * batch-pairs(16) * segs(32) = 8192 -> 2048 blocks of 4 waves
    dim3 grid(H_DIM * 16 * SEG / 4);
    dim3 block(256);
    lwconv_kernel<<<grid, block, 0, stream>>>(x, weight, bias, out);
}

// Round 4
// 57.071 us; speedup vs baseline: 6.3716x; 1.0738x over previous
//
#include <hip/hip_runtime.h>

// LightweightConv1d: x (T,B,C) f32, weight (H,1,K) f32 (softmax over K), bias (C) f32
// out[t,b,c] = bias[c] + sum_k softmax(w[h])[k] * x[t-P+k, b, c],  h = c / (C/H)
#define T_DIM 2048
#define B_DIM 32
#define C_DIM 512
#define H_DIM 16
#define K_DIM 31
#define P_PAD 15
#define SEG 32
#define SEGLEN (T_DIM / SEG)     // 64 time-steps per thread
#define TT 16                    // outputs per chunk
#define WIN (TT + K_DIM - 1)     // 46-element register sliding window
#define STRIDE (B_DIM * C_DIM)   // 16384 floats between consecutive t

// Wave-per-head mapping: each 64-lane wave = 32 channels of ONE head x 2 batches.
// Head index is wave-uniform -> softmaxed weights live in SGPRs (readfirstlane).
// Window pinned in VGPRs via keep-alive asm (defeats load-rematerialization).
// XCD swizzle: the 4 blocks sharing x-rows (same bp,seg; heads 0-15) land on one XCD.
__global__ __launch_bounds__(256, 4)
void lwconv_kernel(const float* __restrict__ x, const float* __restrict__ weight,
                   const float* __restrict__ bias, float* __restrict__ out)
{
    // --- XCD-aware bijective swizzle (2048 blocks = 8 XCDs x 256 slots) ---
    const int p    = blockIdx.x;
    const int xcd  = p & 7;
    const int slot = p >> 3;
    const int L    = (xcd << 8) | ((slot >> 2) << 2) | (slot & 3);  // logical block

    const int wid  = __builtin_amdgcn_readfirstlane((int)(threadIdx.x >> 6));
    const int lane = threadIdx.x & 63;
    const int g    = L * 4 + wid;                 // global wave id, scalar
    const int h    = g & (H_DIM - 1);             // head (wave-uniform)
    const int bp   = (g >> 4) & 15;               // batch pair (uniform)
    const int seg  = g >> 8;                      // t-segment 0..31 (uniform)
    const int c    = (h << 5) | (lane & 31);      // 32 channels of head h
    const int b    = (bp << 1) | (lane >> 5);     // 2 batches per wave

    // per-lane softmax of the head's 31 weights (uniform inputs), then -> SGPR
    float w[K_DIM];
    float m = -3.4e38f;
    #pragma unroll
    for (int k = 0; k < K_DIM; ++k) { w[k] = weight[h * K_DIM + k]; m = fmaxf(m, w[k]); }
    float s = 0.f;
    #pragma unroll
    for (int k = 0; k < K_DIM; ++k) { w[k] = __expf(w[k] - m); s += w[k]; }
    const float inv = 1.f / s;
    unsigned int ws[K_DIM];
    #pragma unroll
    for (int k = 0; k < K_DIM; ++k)
        ws[k] = __builtin_amdgcn_readfirstlane(__float_as_uint(w[k] * inv));

    const float bv = bias[c];
    const float* xp = x + (size_t)b * C_DIM + c;
    float*       op = out + (size_t)b * C_DIM + c;
    const int t0 = seg * SEGLEN;

    // Preload left halo: xw[0..29] = x[t0-15 .. t0+14] (zero below t=0).
    // Upper bound never hit: t0+14 <= 1998 < 2048.
    float xw[WIN];
    #pragma unroll
    for (int i = 0; i < K_DIM - 1; ++i) {
        int t = t0 - P_PAD + i;
        xw[i] = (t >= 0) ? xp[(size_t)t * STRIDE] : 0.f;
        asm volatile("" : "+v"(xw[i]));   // pin halo in VGPRs
    }

    #pragma unroll 1   // rolled: small icache, bounded live range
    for (int chunk = 0; chunk < SEGLEN / TT; ++chunk) {
        const int tb = t0 + chunk * TT;   // outputs tb .. tb+TT-1
        // load leading edge: xw[30..45] = x[tb+15 .. tb+30] (zero past T)
        #pragma unroll
        for (int i = 0; i < TT; ++i) {
            int t = tb + P_PAD + i;
            xw[K_DIM - 1 + i] = (t < T_DIM) ? xp[(size_t)t * STRIDE] : 0.f;
        }
        // compute + store TT outputs, static indexing, weights from SGPR
        #pragma unroll
        for (int i = 0; i < TT; ++i) {
            float acc = bv;
            #pragma unroll
            for (int k = 0; k < K_DIM; ++k)
                acc = fmaf(__uint_as_float(ws[k]), xw[i + k], acc);
            op[(size_t)(tb + i) * STRIDE] = acc;
        }
        // shift window left by TT; keep-alive pins carried values in VGPRs
        #pragma unroll
        for (int i = 0; i < WIN - TT; ++i) {
            xw[i] = xw[i + TT];
            asm volatile("" : "+v"(xw[i]));
        }
    }
}

extern "C" void kernel_launch(void* const* d_in, const int* in_sizes, int n_in,
                              void* d_out, int out_size, void* d_ws, size_t ws_size,
                              hipStream_t stream) {
    const float* x      = (const float*)d_in[0];
    const float* weight = (const float*)d_in[1];
    const float* bias   = (const float*)d_in[2];
    float* out = (float*)d_out;
    // waves = H(16) * batch-pairs(16) * segs(32) = 8192 -> 2048 blocks of 4 waves
    dim3 grid(H_DIM * 16 * SEG / 4);
    dim3 block(256);
    lwconv_kernel<<<grid, block, 0, stream>>>(x, weight, bias, out);
}